// Round 4
// baseline (554.389 us; speedup 1.0000x reference)
//
#include <hip/hip_runtime.h>
#include <math.h>

#define NN 100000   // nodes
#define NE 50000    // edges
#define NSEG (NE + NN)
#define DD 128      // feature dim

// bucketing for the binned CSR build: bucket = id >> 8 (256 segments/bucket)
#define NBE 196
#define NBV 391
#define NB  (NBE + NBV)
#define CAP_E 8960
#define CAP_V 4608

static __device__ __forceinline__ float gelu_exact(float x) {
  return 0.5f * x * (1.0f + erff(x * 0.70710678118654752f));
}

static __device__ __forceinline__ int bucket_base(int g) {
  return (g < NBE) ? g * CAP_E : NBE * CAP_E + (g - NBE) * CAP_V;
}

static __device__ __forceinline__ void acc_bf16x2(float& a0, float& a1, unsigned u) {
  union { unsigned i; float f; } lo, hi;
  lo.i = u << 16;
  hi.i = u & 0xFFFF0000u;
  a0 += lo.f;
  a1 += hi.f;
}

static __device__ __forceinline__ unsigned pack_bf16x2(float a, float b) {
  unsigned ua = __float_as_uint(a), ub = __float_as_uint(b);
  ua = (ua + 0x7FFFu + ((ua >> 16) & 1u)) >> 16;
  ub = (ub + 0x7FFFu + ((ub >> 16) & 1u)) >> 16;
  return ua | (ub << 16);
}

// ---------------- K0: init bucket cursors ----------------
__global__ void k_zero(int* __restrict__ gcur) {
  int g = blockIdx.x * blockDim.x + threadIdx.x;
  if (g < NB) gcur[g] = bucket_base(g);
}

// ---------------- K1: Xp = X @ W ; writes fp32 Xp (d_out) + chunk-major bf16 Xb ----------------
// Xb16 layout: [8 chunks of 16ch][NN][16] bf16
__global__ __launch_bounds__(256) void k_gemm(const float* __restrict__ X,
                                              const float* __restrict__ W,
                                              float* __restrict__ Xp,
                                              unsigned* __restrict__ Xb16) {
  __shared__ float Xs[64 * 128];
  const int tid = threadIdx.x;
  const int rowbase = blockIdx.x * 64;
  const float4* __restrict__ X4 = (const float4*)X;
  float4* Xs4 = (float4*)Xs;
#pragma unroll
  for (int j = 0; j < 8; ++j) {
    int f = tid + j * 256;
    int row = rowbase + (f >> 5);
    float4 v = make_float4(0.f, 0.f, 0.f, 0.f);
    if (row < NN) v = X4[rowbase * 32 + f];
    Xs4[f] = v;
  }
  __syncthreads();
  const int cg = tid & 31;
  const int rg = tid >> 5;
  const float4* __restrict__ W4 = (const float4*)W;
  float4 acc[8];
#pragma unroll
  for (int r = 0; r < 8; ++r) acc[r] = make_float4(0.f, 0.f, 0.f, 0.f);
  for (int kb = 0; kb < 32; ++kb) {
    float4 w0 = W4[(4 * kb + 0) * 32 + cg];
    float4 w1 = W4[(4 * kb + 1) * 32 + cg];
    float4 w2 = W4[(4 * kb + 2) * 32 + cg];
    float4 w3 = W4[(4 * kb + 3) * 32 + cg];
#pragma unroll
    for (int r = 0; r < 8; ++r) {
      float4 xv = *(const float4*)&Xs[(rg * 8 + r) * 128 + 4 * kb];
      acc[r].x = fmaf(xv.x, w0.x, fmaf(xv.y, w1.x, fmaf(xv.z, w2.x, fmaf(xv.w, w3.x, acc[r].x))));
      acc[r].y = fmaf(xv.x, w0.y, fmaf(xv.y, w1.y, fmaf(xv.z, w2.y, fmaf(xv.w, w3.y, acc[r].y))));
      acc[r].z = fmaf(xv.x, w0.z, fmaf(xv.y, w1.z, fmaf(xv.z, w2.z, fmaf(xv.w, w3.z, acc[r].z))));
      acc[r].w = fmaf(xv.x, w0.w, fmaf(xv.y, w1.w, fmaf(xv.z, w2.w, fmaf(xv.w, w3.w, acc[r].w))));
    }
  }
  const int chunk = cg >> 2;        // 16-ch chunk of this 4-col group
  const int sub = cg & 3;           // uint2 slot within chunk row
#pragma unroll
  for (int r = 0; r < 8; ++r) {
    int row = rowbase + rg * 8 + r;
    if (row < NN) {
      ((float4*)Xp)[row * 32 + cg] = acc[r];
      uint2 p;
      p.x = pack_bf16x2(acc[r].x, acc[r].y);
      p.y = pack_bf16x2(acc[r].z, acc[r].w);
      ((uint2*)Xb16)[(chunk * NN + row) * 4 + sub] = p;
    }
  }
}

// ---------------- K2: bin incidences into bucket slabs ----------------
__global__ __launch_bounds__(256) void k_pass1(const int* __restrict__ vertex,
                                               const int* __restrict__ edges,
                                               int* __restrict__ gcur,
                                               int* __restrict__ S, int nnz) {
  __shared__ int hist[NB];
  const int tid = threadIdx.x;
  for (int b = tid; b < NB; b += 256) hist[b] = 0;
  __syncthreads();
  const int base = blockIdx.x * 4096;
#pragma unroll
  for (int k = 0; k < 16; ++k) {
    int i = base + tid + k * 256;
    if (i < nnz) {
      atomicAdd(&hist[edges[i] >> 8], 1);
      atomicAdd(&hist[NBE + (vertex[i] >> 8)], 1);
    }
  }
  __syncthreads();
  for (int b = tid; b < NB; b += 256) {
    int c = hist[b];
    hist[b] = c ? atomicAdd(&gcur[b], c) : 0;
  }
  __syncthreads();
#pragma unroll
  for (int k = 0; k < 16; ++k) {
    int i = base + tid + k * 256;
    if (i < nnz) {
      int e = edges[i], v = vertex[i];
      int pe = atomicAdd(&hist[e >> 8], 1);
      S[pe] = ((e & 255) << 17) | v;
      int pv = atomicAdd(&hist[NBE + (v >> 8)], 1);
      S[pv] = ((v & 255) << 17) | e;
    }
  }
}

// ---------------- K3: exclusive scan of bucket counts ----------------
__global__ __launch_bounds__(1024) void k_bscan(const int* __restrict__ gcur,
                                                int* __restrict__ gbase) {
  __shared__ int s[1024];
  const int g = threadIdx.x;
  int cnt = 0;
  if (g < NB) cnt = gcur[g] - bucket_base(g);
  s[g] = cnt;
  __syncthreads();
  for (int off = 1; off < 1024; off <<= 1) {
    int y = (g >= off) ? s[g - off] : 0;
    __syncthreads();
    s[g] += y;
    __syncthreads();
  }
  if (g < NB) gbase[g] = s[g] - cnt;
}

// ---------------- K4: per-bucket LDS counting sort -> L, O ----------------
__global__ __launch_bounds__(256) void k_pass2(const int* __restrict__ gcur,
                                               const int* __restrict__ gbase,
                                               const int* __restrict__ S,
                                               int* __restrict__ L,
                                               int* __restrict__ O) {
  __shared__ int offs[257];
  __shared__ int cur[256];
  __shared__ int scratch[CAP_E];
  const int g = blockIdx.x;
  const int tid = threadIdx.x;
  const bool isE = g < NBE;
  const int sstart = bucket_base(g);
  int nit = gcur[g] - sstart;
  const int cap = isE ? CAP_E : CAP_V;
  if (nit > cap) nit = cap;
  const int s0 = isE ? (g << 8) : ((g - NBE) << 8);
  const int segN = min(256, (isE ? NE : NN) - s0);
  const int obase = isE ? s0 : NE + s0;
  const int dbase = gbase[g];
  for (int k = tid; k < 257; k += 256) offs[k] = 0;
  __syncthreads();
  for (int t = tid; t < nit; t += 256) atomicAdd(&offs[(S[sstart + t] >> 17) + 1], 1);
  __syncthreads();
  for (int off = 1; off < 256; off <<= 1) {
    int y = (tid >= off) ? offs[tid + 1 - off] : 0;
    __syncthreads();
    offs[tid + 1] += y;
    __syncthreads();
  }
  cur[tid] = offs[tid];
  __syncthreads();
  for (int t = tid; t < nit; t += 256) {
    int u = S[sstart + t];
    int r = atomicAdd(&cur[u >> 17], 1);
    scratch[r] = u & 0x1FFFF;
  }
  __syncthreads();
  for (int t = tid; t < nit; t += 256) L[dbase + t] = scratch[t];
  for (int k = tid; k <= segN; k += 256) O[obase + k] = dbase + offs[k];
}

// ---------------- K5: edge aggregate, chunked (8 x 16ch) ----------------
// 2 lanes own one edge; chunk = blockIdx.y; source chunk is 3.2 MB (L2-resident).
// Xe16 layout: [4 superchunks of 32ch][NE][32] bf16
__global__ __launch_bounds__(256) void k_edge_agg(const unsigned* __restrict__ Xb16,
                                                  const int* __restrict__ O,
                                                  const int* __restrict__ L,
                                                  unsigned* __restrict__ Xe16) {
  const int tid = threadIdx.x;
  const int e = blockIdx.x * 128 + (tid >> 1);
  const int c = blockIdx.y;           // 16-ch chunk 0..7
  const int h = tid & 1;              // 8-elt half of the 16-ch row
  if (e >= NE) return;
  const int start = O[e];
  const int end = O[e + 1];
  const uint4* __restrict__ P = (const uint4*)Xb16;   // row-chunk = 2 uint4
  const int pb = c * NN * 2 + h;      // uint4 index base: (c*NN+v)*2 + h
  float a[8];
#pragma unroll
  for (int k = 0; k < 8; ++k) a[k] = 0.f;
  int j = start;
  for (; j + 1 < end; j += 2) {
    int v0 = L[j], v1 = L[j + 1];
    uint4 u0 = P[pb + v0 * 2];
    uint4 u1 = P[pb + v1 * 2];
    acc_bf16x2(a[0], a[1], u0.x); acc_bf16x2(a[2], a[3], u0.y);
    acc_bf16x2(a[4], a[5], u0.z); acc_bf16x2(a[6], a[7], u0.w);
    acc_bf16x2(a[0], a[1], u1.x); acc_bf16x2(a[2], a[3], u1.y);
    acc_bf16x2(a[4], a[5], u1.z); acc_bf16x2(a[6], a[7], u1.w);
  }
  if (j < end) {
    uint4 u0 = P[pb + L[j] * 2];
    acc_bf16x2(a[0], a[1], u0.x); acc_bf16x2(a[2], a[3], u0.y);
    acc_bf16x2(a[4], a[5], u0.z); acc_bf16x2(a[6], a[7], u0.w);
  }
  uint4 o;
  o.x = pack_bf16x2(a[0], a[1]);
  o.y = pack_bf16x2(a[2], a[3]);
  o.z = pack_bf16x2(a[4], a[5]);
  o.w = pack_bf16x2(a[6], a[7]);
  // dest uint4 index: ((c>>1)*NE + e)*4 + 2*(c&1) + h
  ((uint4*)Xe16)[((c >> 1) * NE + e) * 4 + 2 * (c & 1) + h] = o;
}

// ---------------- K6: vertex aggregate + GELU, chunked (4 x 32ch) ----------------
// 4 lanes own one vertex; source chunk is 3.2 MB (L2-resident).
__global__ __launch_bounds__(256) void k_vert_agg(const unsigned* __restrict__ Xe16,
                                                  const int* __restrict__ O,
                                                  const int* __restrict__ L,
                                                  const float* __restrict__ eps,
                                                  float* __restrict__ XpOut) {
  const int tid = threadIdx.x;
  const int v = blockIdx.x * 64 + (tid >> 2);
  const int cb = blockIdx.y;          // 32-ch superchunk 0..3
  const int ql = tid & 3;             // 8-elt quarter of the 32-ch row
  if (v >= NN) return;
  const int start = O[NE + v];
  const int end = O[NE + v + 1];
  const uint4* __restrict__ Q = (const uint4*)Xe16;   // row-chunk = 4 uint4
  const int qb = cb * NE * 4 + ql;    // uint4 index base: (cb*NE+e)*4 + ql
  float a[8];
#pragma unroll
  for (int k = 0; k < 8; ++k) a[k] = 0.f;
  int j = start;
  for (; j + 1 < end; j += 2) {
    int e0 = L[j], e1 = L[j + 1];
    uint4 u0 = Q[qb + e0 * 4];
    uint4 u1 = Q[qb + e1 * 4];
    acc_bf16x2(a[0], a[1], u0.x); acc_bf16x2(a[2], a[3], u0.y);
    acc_bf16x2(a[4], a[5], u0.z); acc_bf16x2(a[6], a[7], u0.w);
    acc_bf16x2(a[0], a[1], u1.x); acc_bf16x2(a[2], a[3], u1.y);
    acc_bf16x2(a[4], a[5], u1.z); acc_bf16x2(a[6], a[7], u1.w);
  }
  if (j < end) {
    uint4 u0 = Q[qb + L[j] * 4];
    acc_bf16x2(a[0], a[1], u0.x); acc_bf16x2(a[2], a[3], u0.y);
    acc_bf16x2(a[4], a[5], u0.z); acc_bf16x2(a[6], a[7], u0.w);
  }
  // epilogue: lane owns fp32 channels [cb*32 + 8*ql, +8) of Xp/out
  float4* P2 = (float4*)XpOut;
  const int fb = v * 32 + cb * 8 + ql * 2;
  float4 x0 = P2[fb];
  float4 x1 = P2[fb + 1];
  float s = 1.0f + eps[0];
  x0.x = gelu_exact(fmaf(s, x0.x, a[0]));
  x0.y = gelu_exact(fmaf(s, x0.y, a[1]));
  x0.z = gelu_exact(fmaf(s, x0.z, a[2]));
  x0.w = gelu_exact(fmaf(s, x0.w, a[3]));
  x1.x = gelu_exact(fmaf(s, x1.x, a[4]));
  x1.y = gelu_exact(fmaf(s, x1.y, a[5]));
  x1.z = gelu_exact(fmaf(s, x1.z, a[6]));
  x1.w = gelu_exact(fmaf(s, x1.w, a[7]));
  P2[fb] = x0;
  P2[fb + 1] = x1;
}

extern "C" void kernel_launch(void* const* d_in, const int* in_sizes, int n_in,
                              void* d_out, int out_size, void* d_ws, size_t ws_size,
                              hipStream_t stream) {
  const float* X = (const float*)d_in[0];
  const float* W = (const float*)d_in[1];
  const float* eps = (const float*)d_in[2];
  const int* vertex = (const int*)d_in[3];
  const int* edges = (const int*)d_in[4];
  const int nnz = in_sizes[3];

  char* ws = (char*)d_ws;
  size_t off = 0;
  auto alloc = [&](size_t bytes) -> void* {
    void* p = ws + off;
    off = (off + bytes + 255) & ~(size_t)255;
    return p;
  };
  const size_t stagingB = ((size_t)NBE * CAP_E + (size_t)NBV * CAP_V) * 4;  // ~14.2 MB
  const size_t xbB = (size_t)NN * DD * 2;                                   // 25.6 MB
  void* A = alloc(xbB > stagingB ? xbB : stagingB);
  int* S = (int*)A;              // staging slabs (dead after k_pass2)
  unsigned* Xb16 = (unsigned*)A; // chunk-major bf16 Xp (born in k_gemm)
  unsigned* Xe16 = (unsigned*)alloc((size_t)NE * DD * 2);   // 12.8 MB
  int* L = (int*)alloc((size_t)2 * nnz * sizeof(int));      // 12.8 MB
  int* O = (int*)alloc((size_t)(NSEG + 1) * sizeof(int));
  int* gcur = (int*)alloc((size_t)NB * sizeof(int));
  int* gbase = (int*)alloc((size_t)NB * sizeof(int));
  if (off > ws_size) return;

  float* Xp = (float*)d_out;

  k_zero<<<3, 256, 0, stream>>>(gcur);
  k_pass1<<<(nnz + 4095) / 4096, 256, 0, stream>>>(vertex, edges, gcur, S, nnz);
  k_bscan<<<1, 1024, 0, stream>>>(gcur, gbase);
  k_pass2<<<NB, 256, 0, stream>>>(gcur, gbase, S, L, O);
  k_gemm<<<(NN + 63) / 64, 256, 0, stream>>>(X, W, Xp, Xb16);
  dim3 ga((NE + 127) / 128, 8);
  k_edge_agg<<<ga, 256, 0, stream>>>(Xb16, O, L, Xe16);
  dim3 gb((NN + 63) / 64, 4);
  k_vert_agg<<<gb, 256, 0, stream>>>(Xe16, O, L, eps, Xp);
}

// Round 5
// 456.334 us; speedup vs baseline: 1.2149x; 1.2149x over previous
//
#include <hip/hip_runtime.h>
#include <math.h>

#define NN 100000   // nodes
#define NE 50000    // edges
#define NSEG (NE + NN)
#define DD 128      // feature dim

// bucketing for the binned CSR build: bucket = id >> 8 (256 segments/bucket)
#define NBE 196
#define NBV 391
#define NB  (NBE + NBV)
#define CAP_E 8960
#define CAP_V 4608

static __device__ __forceinline__ float gelu_exact(float x) {
  return 0.5f * x * (1.0f + erff(x * 0.70710678118654752f));
}

static __device__ __forceinline__ int bucket_base(int g) {
  return (g < NBE) ? g * CAP_E : NBE * CAP_E + (g - NBE) * CAP_V;
}

static __device__ __forceinline__ void acc_bf16x2(float& a0, float& a1, unsigned u) {
  union { unsigned i; float f; } lo, hi;
  lo.i = u << 16;
  hi.i = u & 0xFFFF0000u;
  a0 += lo.f;
  a1 += hi.f;
}

static __device__ __forceinline__ unsigned pack_bf16x2(float a, float b) {
  unsigned ua = __float_as_uint(a), ub = __float_as_uint(b);
  ua = (ua + 0x7FFFu + ((ua >> 16) & 1u)) >> 16;
  ub = (ub + 0x7FFFu + ((ub >> 16) & 1u)) >> 16;
  return ua | (ub << 16);
}

// ---------------- K0: init bucket cursors ----------------
__global__ void k_zero(int* __restrict__ gcur) {
  int g = blockIdx.x * blockDim.x + threadIdx.x;
  if (g < NB) gcur[g] = bucket_base(g);
}

// ---------------- K1: Xp = X @ W ; fp32 Xp (d_out) + chunk-major bf16 Xb ----------------
// Xb16 layout: [8 chunks of 16ch][NN][16] bf16
__global__ __launch_bounds__(256) void k_gemm(const float* __restrict__ X,
                                              const float* __restrict__ W,
                                              float* __restrict__ Xp,
                                              unsigned* __restrict__ Xb16) {
  __shared__ float Xs[64 * 128];
  const int tid = threadIdx.x;
  const int rowbase = blockIdx.x * 64;
  const float4* __restrict__ X4 = (const float4*)X;
  float4* Xs4 = (float4*)Xs;
#pragma unroll
  for (int j = 0; j < 8; ++j) {
    int f = tid + j * 256;
    int row = rowbase + (f >> 5);
    float4 v = make_float4(0.f, 0.f, 0.f, 0.f);
    if (row < NN) v = X4[rowbase * 32 + f];
    Xs4[f] = v;
  }
  __syncthreads();
  const int cg = tid & 31;
  const int rg = tid >> 5;
  const float4* __restrict__ W4 = (const float4*)W;
  float4 acc[8];
#pragma unroll
  for (int r = 0; r < 8; ++r) acc[r] = make_float4(0.f, 0.f, 0.f, 0.f);
  for (int kb = 0; kb < 32; ++kb) {
    float4 w0 = W4[(4 * kb + 0) * 32 + cg];
    float4 w1 = W4[(4 * kb + 1) * 32 + cg];
    float4 w2 = W4[(4 * kb + 2) * 32 + cg];
    float4 w3 = W4[(4 * kb + 3) * 32 + cg];
#pragma unroll
    for (int r = 0; r < 8; ++r) {
      float4 xv = *(const float4*)&Xs[(rg * 8 + r) * 128 + 4 * kb];
      acc[r].x = fmaf(xv.x, w0.x, fmaf(xv.y, w1.x, fmaf(xv.z, w2.x, fmaf(xv.w, w3.x, acc[r].x))));
      acc[r].y = fmaf(xv.x, w0.y, fmaf(xv.y, w1.y, fmaf(xv.z, w2.y, fmaf(xv.w, w3.y, acc[r].y))));
      acc[r].z = fmaf(xv.x, w0.z, fmaf(xv.y, w1.z, fmaf(xv.z, w2.z, fmaf(xv.w, w3.z, acc[r].z))));
      acc[r].w = fmaf(xv.x, w0.w, fmaf(xv.y, w1.w, fmaf(xv.z, w2.w, fmaf(xv.w, w3.w, acc[r].w))));
    }
  }
  const int chunk = cg >> 2;
  const int sub = cg & 3;
#pragma unroll
  for (int r = 0; r < 8; ++r) {
    int row = rowbase + rg * 8 + r;
    if (row < NN) {
      ((float4*)Xp)[row * 32 + cg] = acc[r];
      uint2 p;
      p.x = pack_bf16x2(acc[r].x, acc[r].y);
      p.y = pack_bf16x2(acc[r].z, acc[r].w);
      ((uint2*)Xb16)[(chunk * NN + row) * 4 + sub] = p;
    }
  }
}

// ---------------- K2: bin incidences into bucket slabs ----------------
__global__ __launch_bounds__(256) void k_pass1(const int* __restrict__ vertex,
                                               const int* __restrict__ edges,
                                               int* __restrict__ gcur,
                                               int* __restrict__ S, int nnz) {
  __shared__ int hist[NB];
  const int tid = threadIdx.x;
  for (int b = tid; b < NB; b += 256) hist[b] = 0;
  __syncthreads();
  const int base = blockIdx.x * 4096;
#pragma unroll
  for (int k = 0; k < 16; ++k) {
    int i = base + tid + k * 256;
    if (i < nnz) {
      atomicAdd(&hist[edges[i] >> 8], 1);
      atomicAdd(&hist[NBE + (vertex[i] >> 8)], 1);
    }
  }
  __syncthreads();
  for (int b = tid; b < NB; b += 256) {
    int c = hist[b];
    hist[b] = c ? atomicAdd(&gcur[b], c) : 0;
  }
  __syncthreads();
#pragma unroll
  for (int k = 0; k < 16; ++k) {
    int i = base + tid + k * 256;
    if (i < nnz) {
      int e = edges[i], v = vertex[i];
      int pe = atomicAdd(&hist[e >> 8], 1);
      S[pe] = ((e & 255) << 17) | v;
      int pv = atomicAdd(&hist[NBE + (v >> 8)], 1);
      S[pv] = ((v & 255) << 17) | e;
    }
  }
}

// ---------------- K3: exclusive scan of bucket counts ----------------
__global__ __launch_bounds__(1024) void k_bscan(const int* __restrict__ gcur,
                                                int* __restrict__ gbase) {
  __shared__ int s[1024];
  const int g = threadIdx.x;
  int cnt = 0;
  if (g < NB) cnt = gcur[g] - bucket_base(g);
  s[g] = cnt;
  __syncthreads();
  for (int off = 1; off < 1024; off <<= 1) {
    int y = (g >= off) ? s[g - off] : 0;
    __syncthreads();
    s[g] += y;
    __syncthreads();
  }
  if (g < NB) gbase[g] = s[g] - cnt;
}

// ---------------- K4: per-bucket LDS counting sort -> L, O ----------------
__global__ __launch_bounds__(256) void k_pass2(const int* __restrict__ gcur,
                                               const int* __restrict__ gbase,
                                               const int* __restrict__ S,
                                               int* __restrict__ L,
                                               int* __restrict__ O) {
  __shared__ int offs[257];
  __shared__ int cur[256];
  __shared__ int scratch[CAP_E];
  const int g = blockIdx.x;
  const int tid = threadIdx.x;
  const bool isE = g < NBE;
  const int sstart = bucket_base(g);
  int nit = gcur[g] - sstart;
  const int cap = isE ? CAP_E : CAP_V;
  if (nit > cap) nit = cap;
  const int s0 = isE ? (g << 8) : ((g - NBE) << 8);
  const int segN = min(256, (isE ? NE : NN) - s0);
  const int obase = isE ? s0 : NE + s0;
  const int dbase = gbase[g];
  for (int k = tid; k < 257; k += 256) offs[k] = 0;
  __syncthreads();
  for (int t = tid; t < nit; t += 256) atomicAdd(&offs[(S[sstart + t] >> 17) + 1], 1);
  __syncthreads();
  for (int off = 1; off < 256; off <<= 1) {
    int y = (tid >= off) ? offs[tid + 1 - off] : 0;
    __syncthreads();
    offs[tid + 1] += y;
    __syncthreads();
  }
  cur[tid] = offs[tid];
  __syncthreads();
  for (int t = tid; t < nit; t += 256) {
    int u = S[sstart + t];
    int r = atomicAdd(&cur[u >> 17], 1);
    scratch[r] = u & 0x1FFFF;
  }
  __syncthreads();
  for (int t = tid; t < nit; t += 256) L[dbase + t] = scratch[t];
  for (int k = tid; k <= segN; k += 256) O[obase + k] = dbase + offs[k];
}

// ---------------- K5: edge aggregate, XCD-pinned chunks ----------------
// chunk = blockIdx.x & 7 (XCD round-robin heuristic); 2 lanes own one edge.
// Xe16 layout: [8 chunks of 16ch][NE][16] bf16
__global__ __launch_bounds__(256) void k_edge_agg(const unsigned* __restrict__ Xb16,
                                                  const int* __restrict__ O,
                                                  const int* __restrict__ L,
                                                  unsigned* __restrict__ Xe16) {
  const int tid = threadIdx.x;
  const int c = blockIdx.x & 7;               // chunk -> pinned to one XCD
  const int e = (blockIdx.x >> 3) * 128 + (tid >> 1);
  const int h = tid & 1;                      // 8-ch half of the 16-ch row
  if (e >= NE) return;
  const int start = O[e];
  const int end = O[e + 1];
  const uint4* __restrict__ P = (const uint4*)Xb16;   // chunk row = 2 uint4
  const int pb = c * NN * 2 + h;
  float a[8];
#pragma unroll
  for (int k = 0; k < 8; ++k) a[k] = 0.f;
  int j = start;
  for (; j + 1 < end; j += 2) {
    int v0 = L[j], v1 = L[j + 1];
    uint4 u0 = P[pb + v0 * 2];
    uint4 u1 = P[pb + v1 * 2];
    acc_bf16x2(a[0], a[1], u0.x); acc_bf16x2(a[2], a[3], u0.y);
    acc_bf16x2(a[4], a[5], u0.z); acc_bf16x2(a[6], a[7], u0.w);
    acc_bf16x2(a[0], a[1], u1.x); acc_bf16x2(a[2], a[3], u1.y);
    acc_bf16x2(a[4], a[5], u1.z); acc_bf16x2(a[6], a[7], u1.w);
  }
  if (j < end) {
    uint4 u0 = P[pb + L[j] * 2];
    acc_bf16x2(a[0], a[1], u0.x); acc_bf16x2(a[2], a[3], u0.y);
    acc_bf16x2(a[4], a[5], u0.z); acc_bf16x2(a[6], a[7], u0.w);
  }
  uint4 o;
  o.x = pack_bf16x2(a[0], a[1]);
  o.y = pack_bf16x2(a[2], a[3]);
  o.z = pack_bf16x2(a[4], a[5]);
  o.w = pack_bf16x2(a[6], a[7]);
  ((uint4*)Xe16)[(c * NE + e) * 2 + h] = o;
}

// ---------------- K6: vertex aggregate + GELU, XCD-pinned chunks ----------------
// chunk = blockIdx.x & 7; 2 lanes own one vertex; source slice 1.6 MB / XCD.
__global__ __launch_bounds__(256) void k_vert_agg(const unsigned* __restrict__ Xe16,
                                                  const int* __restrict__ O,
                                                  const int* __restrict__ L,
                                                  const float* __restrict__ eps,
                                                  float* __restrict__ XpOut) {
  const int tid = threadIdx.x;
  const int c = blockIdx.x & 7;
  const int v = (blockIdx.x >> 3) * 128 + (tid >> 1);
  const int h = tid & 1;
  if (v >= NN) return;
  const int start = O[NE + v];
  const int end = O[NE + v + 1];
  const uint4* __restrict__ Q = (const uint4*)Xe16;
  const int qb = c * NE * 2 + h;
  float a[8];
#pragma unroll
  for (int k = 0; k < 8; ++k) a[k] = 0.f;
  int j = start;
  for (; j + 1 < end; j += 2) {
    int e0 = L[j], e1 = L[j + 1];
    uint4 u0 = Q[qb + e0 * 2];
    uint4 u1 = Q[qb + e1 * 2];
    acc_bf16x2(a[0], a[1], u0.x); acc_bf16x2(a[2], a[3], u0.y);
    acc_bf16x2(a[4], a[5], u0.z); acc_bf16x2(a[6], a[7], u0.w);
    acc_bf16x2(a[0], a[1], u1.x); acc_bf16x2(a[2], a[3], u1.y);
    acc_bf16x2(a[4], a[5], u1.z); acc_bf16x2(a[6], a[7], u1.w);
  }
  if (j < end) {
    uint4 u0 = Q[qb + L[j] * 2];
    acc_bf16x2(a[0], a[1], u0.x); acc_bf16x2(a[2], a[3], u0.y);
    acc_bf16x2(a[4], a[5], u0.z); acc_bf16x2(a[6], a[7], u0.w);
  }
  // epilogue: lane owns fp32 channels [c*16 + h*8, +8)
  float4* P2 = (float4*)XpOut;
  const int fb = v * 32 + c * 4 + h * 2;
  float4 x0 = P2[fb];
  float4 x1 = P2[fb + 1];
  float s = 1.0f + eps[0];
  x0.x = gelu_exact(fmaf(s, x0.x, a[0]));
  x0.y = gelu_exact(fmaf(s, x0.y, a[1]));
  x0.z = gelu_exact(fmaf(s, x0.z, a[2]));
  x0.w = gelu_exact(fmaf(s, x0.w, a[3]));
  x1.x = gelu_exact(fmaf(s, x1.x, a[4]));
  x1.y = gelu_exact(fmaf(s, x1.y, a[5]));
  x1.z = gelu_exact(fmaf(s, x1.z, a[6]));
  x1.w = gelu_exact(fmaf(s, x1.w, a[7]));
  P2[fb] = x0;
  P2[fb + 1] = x1;
}

extern "C" void kernel_launch(void* const* d_in, const int* in_sizes, int n_in,
                              void* d_out, int out_size, void* d_ws, size_t ws_size,
                              hipStream_t stream) {
  const float* X = (const float*)d_in[0];
  const float* W = (const float*)d_in[1];
  const float* eps = (const float*)d_in[2];
  const int* vertex = (const int*)d_in[3];
  const int* edges = (const int*)d_in[4];
  const int nnz = in_sizes[3];

  char* ws = (char*)d_ws;
  size_t off = 0;
  auto alloc = [&](size_t bytes) -> void* {
    void* p = ws + off;
    off = (off + bytes + 255) & ~(size_t)255;
    return p;
  };
  const size_t stagingB = ((size_t)NBE * CAP_E + (size_t)NBV * CAP_V) * 4;  // ~14.2 MB
  const size_t xbB = (size_t)NN * DD * 2;                                   // 25.6 MB
  void* A = alloc(xbB > stagingB ? xbB : stagingB);
  int* S = (int*)A;              // staging slabs (dead after k_pass2)
  unsigned* Xb16 = (unsigned*)A; // chunk-major bf16 Xp (born in k_gemm)
  unsigned* Xe16 = (unsigned*)alloc((size_t)NE * DD * 2);   // 12.8 MB
  int* L = (int*)alloc((size_t)2 * nnz * sizeof(int));      // 12.8 MB
  int* O = (int*)alloc((size_t)(NSEG + 1) * sizeof(int));
  int* gcur = (int*)alloc((size_t)NB * sizeof(int));
  int* gbase = (int*)alloc((size_t)NB * sizeof(int));
  if (off > ws_size) return;

  float* Xp = (float*)d_out;

  k_zero<<<3, 256, 0, stream>>>(gcur);
  k_pass1<<<(nnz + 4095) / 4096, 256, 0, stream>>>(vertex, edges, gcur, S, nnz);
  k_bscan<<<1, 1024, 0, stream>>>(gcur, gbase);
  k_pass2<<<NB, 256, 0, stream>>>(gcur, gbase, S, L, O);
  k_gemm<<<(NN + 63) / 64, 256, 0, stream>>>(X, W, Xp, Xb16);
  k_edge_agg<<<8 * ((NE + 127) / 128), 256, 0, stream>>>(Xb16, O, L, Xe16);
  k_vert_agg<<<8 * ((NN + 127) / 128), 256, 0, stream>>>(Xe16, O, L, eps, Xp);
}